// Round 8
// baseline (35.313 us; speedup 1.0000x reference)
//
#include <hip/hip_runtime.h>
#include <hip/hip_bf16.h>

// FilterbankLinear: out[b, j*8+o] = sum_{c,t} x[b,c,s_j+t] * w[j*8+o, c*32+t]
// s_j = j (j<4063), s_4063 = 4064.
// Base = round-3 best (29.4us): block = 8 windows, 4 waves, x LDS-staged via
// coalesced global_load_lds dwordx4 double-buffered, w float4 register
// prefetch, one __syncthreads per channel.
// NEW: w loads + out stores are NON-TEMPORAL (single-use data; avoid L3
// allocation -> avoid dirty-line eviction writebacks from the harness fills).

#define NF 4096
#define NC 21
#define WIN 32
#define OC 8
#define NWIN 4064
#define NKTOT (OC * NWIN)
#define DD (NC * WIN)       // 672
#define JB 8
#define NBLK (NWIN / JB)    // 508
#define XROWB 272           // 17 chunks * 16B per x row in LDS
#define XBUFB 9216          // 576 chunks * 16B per buffer

typedef short short8 __attribute__((ext_vector_type(8)));
typedef float f32x4 __attribute__((ext_vector_type(4)));

static __device__ __forceinline__ short f2bf(float f) {
  __bf16 h = (__bf16)f;
  return __builtin_bit_cast(short, h);
}
static __device__ __forceinline__ short8 pk8(float a, float b, float c, float d,
                                             float e, float f, float g, float h) {
  short8 v;
  v[0]=f2bf(a); v[1]=f2bf(b); v[2]=f2bf(c); v[3]=f2bf(d);
  v[4]=f2bf(e); v[5]=f2bf(f); v[6]=f2bf(g); v[7]=f2bf(h);
  return v;
}
// select 8 consecutive floats out of 12 by wave-uniform u (static indices only)
static __device__ __forceinline__ short8 sel8(f32x4 a, f32x4 b, f32x4 c, int u) {
  switch (u & 3) {
    case 0:  return pk8(a[0],a[1],a[2],a[3],b[0],b[1],b[2],b[3]);
    case 1:  return pk8(a[1],a[2],a[3],b[0],b[1],b[2],b[3],c[0]);
    case 2:  return pk8(a[2],a[3],b[0],b[1],b[2],b[3],c[0],c[1]);
    default: return pk8(a[3],b[0],b[1],b[2],b[3],c[0],c[1],c[2]);
  }
}
// non-temporal float4 load (16B-aligned)
static __device__ __forceinline__ f32x4 ntld4(const float* p) {
  return __builtin_nontemporal_load((const f32x4*)p);
}

#define STAGE(GP, I, NB) \
  __builtin_amdgcn_global_load_lds( \
    (const __attribute__((address_space(1))) unsigned int*)(GP), \
    (__attribute__((address_space(3))) unsigned int*)(xlds + (NB)*XBUFB + (I)*1024), \
    16, 0, 0)

__global__ __launch_bounds__(256) void fb_nt(const float* __restrict__ x,
                                             const float* __restrict__ w,
                                             float* __restrict__ out) {
  __shared__ __align__(16) char xlds[2 * XBUFB];
  const int lane = threadIdx.x & 63;
  const int wv   = threadIdx.x >> 6;

  // bijective XCD swizzle (nwg=508: q=63, r=4)
  const int orig = blockIdx.x;
  const int xcd = orig & 7, idx = orig >> 3;
  const int blk = (xcd < 4 ? xcd * 64 : 256 + (xcd - 4) * 63) + idx;
  const int j0 = blk * JB;
  const int a0 = (j0 < NF - 68) ? j0 : (NF - 68);   // staged span base

  const int n  = lane & 15;
  const int o  = n & 7;
  const int Ck = (lane >> 4) * 2;
  const int boff0 = n * XROWB, boff1 = (16 + n) * XROWB;

  const int jg0 = j0 + 2 * wv, jg1 = jg0 + 1;
  const int s1v = (jg1 == NWIN - 1) ? (NF - WIN) : jg1;
  const int rj0 = jg0 - a0, rj1 = s1v - a0;
  const int u0 = rj0 & 3, u1 = rj1 & 3;
  const int Cw0 = rj0 >> 2, Cw1 = rj1 >> 2;

  // x staging thread coords: instrs i = 2wv, 2wv+1, plus i=8 on wave 0
  const int i0 = 2 * wv, i1 = 2 * wv + 1;
  int q0 = i0 * 64 + lane, q1 = i1 * 64 + lane, q2 = 512 + lane;
  if (q2 > 543) q2 = 543;                // clamp tail lanes (dup-write into pad)
  const int b0 = q0 / 17, p0 = q0 - b0 * 17;
  const int b1 = q1 / 17, p1 = q1 - b1 * 17;
  const int b2 = q2 / 17, p2 = q2 - b2 * 17;
  const float* xs0 = x + (size_t)b0 * (NC * NF) + a0 + p0 * 4;
  const float* xs1 = x + (size_t)b1 * (NC * NF) + a0 + p1 * 4;
  const float* xs2 = x + (size_t)b2 * (NC * NF) + a0 + p2 * 4;

  const float* wn0 = w + ((size_t)jg0 * OC + o) * DD + Ck * 4;
  const float* wn1 = w + ((size_t)jg1 * OC + o) * DD + Ck * 4;

  f32x4 acc00 = {0,0,0,0}, acc01 = {0,0,0,0}, acc10 = {0,0,0,0}, acc11 = {0,0,0,0};

  // ---- prologue: stage + load channel 0 ----
  STAGE(xs0, i0, 0); xs0 += NF;
  STAGE(xs1, i1, 0); xs1 += NF;
  if (wv == 0) { STAGE(xs2, 8, 0); xs2 += NF; }
  f32x4 w0a = ntld4(wn0), w0b = ntld4(wn0 + 4);
  f32x4 w1a = ntld4(wn1), w1b = ntld4(wn1 + 4);
  wn0 += WIN; wn1 += WIN;
  __syncthreads();

  int buf = 0;
  for (int c = 0; c < NC; ++c) {
    f32x4 w0an = {0,0,0,0}, w0bn = {0,0,0,0}, w1an = {0,0,0,0}, w1bn = {0,0,0,0};
    if (c < NC - 1) {  // issue next channel's staging + w prefetch before compute
      STAGE(xs0, i0, buf ^ 1); xs0 += NF;
      STAGE(xs1, i1, buf ^ 1); xs1 += NF;
      if (wv == 0) { STAGE(xs2, 8, buf ^ 1); xs2 += NF; }
      w0an = ntld4(wn0); w0bn = ntld4(wn0 + 4);
      w1an = ntld4(wn1); w1bn = ntld4(wn1 + 4);
      wn0 += WIN; wn1 += WIN;
    }
    const char* xb = xlds + buf * XBUFB;
    {   // window 0
      short8 fbw = pk8(w0a[0],w0a[1],w0a[2],w0a[3],w0b[0],w0b[1],w0b[2],w0b[3]);
      int off = boff0 + (Cw0 + Ck) * 16;
      f32x4 ra = *(const f32x4*)(xb + off);
      f32x4 rb = *(const f32x4*)(xb + off + 16);
      f32x4 rc = *(const f32x4*)(xb + off + 32);
      acc00 = __builtin_amdgcn_mfma_f32_16x16x32_bf16(sel8(ra,rb,rc,u0), fbw, acc00, 0,0,0);
      off = boff1 + (Cw0 + Ck) * 16;
      ra = *(const f32x4*)(xb + off);
      rb = *(const f32x4*)(xb + off + 16);
      rc = *(const f32x4*)(xb + off + 32);
      acc01 = __builtin_amdgcn_mfma_f32_16x16x32_bf16(sel8(ra,rb,rc,u0), fbw, acc01, 0,0,0);
    }
    {   // window 1
      short8 fbw = pk8(w1a[0],w1a[1],w1a[2],w1a[3],w1b[0],w1b[1],w1b[2],w1b[3]);
      int off = boff0 + (Cw1 + Ck) * 16;
      f32x4 ra = *(const f32x4*)(xb + off);
      f32x4 rb = *(const f32x4*)(xb + off + 16);
      f32x4 rc = *(const f32x4*)(xb + off + 32);
      acc10 = __builtin_amdgcn_mfma_f32_16x16x32_bf16(sel8(ra,rb,rc,u1), fbw, acc10, 0,0,0);
      off = boff1 + (Cw1 + Ck) * 16;
      ra = *(const f32x4*)(xb + off);
      rb = *(const f32x4*)(xb + off + 16);
      rc = *(const f32x4*)(xb + off + 32);
      acc11 = __builtin_amdgcn_mfma_f32_16x16x32_bf16(sel8(ra,rb,rc,u1), fbw, acc11, 0,0,0);
    }
    __syncthreads();      // drains vmcnt: buf^1 staged, w prefetch landed
    w0a = w0an; w0b = w0bn; w1a = w1an; w1b = w1bn;
    buf ^= 1;
  }

  if (n < 8) {
    const int m0 = (lane >> 4) * 4;
    #pragma unroll
    for (int e = 0; e < 4; ++e) {
      __builtin_nontemporal_store(acc00[e],
        out + (size_t)(m0 + e)      * NKTOT + (size_t)jg0 * OC + n);
      __builtin_nontemporal_store(acc01[e],
        out + (size_t)(m0 + e + 16) * NKTOT + (size_t)jg0 * OC + n);
      __builtin_nontemporal_store(acc10[e],
        out + (size_t)(m0 + e)      * NKTOT + (size_t)jg1 * OC + n);
      __builtin_nontemporal_store(acc11[e],
        out + (size_t)(m0 + e + 16) * NKTOT + (size_t)jg1 * OC + n);
    }
  }
}

extern "C" void kernel_launch(void* const* d_in, const int* in_sizes, int n_in,
                              void* d_out, int out_size, void* d_ws, size_t ws_size,
                              hipStream_t stream) {
  const float* x = (const float*)d_in[0];
  const float* w = (const float*)d_in[1];
  float* out = (float*)d_out;
  dim3 grid(NBLK), block(256);
  hipLaunchKernelGGL(fb_nt, grid, block, 0, stream, x, w, out);
}

// Round 9
// 31.366 us; speedup vs baseline: 1.1258x; 1.1258x over previous
//
#include <hip/hip_runtime.h>
#include <hip/hip_bf16.h>

// FilterbankLinear: out[b, j*8+o] = sum_{c,t} x[b,c,s_j+t] * w[j*8+o, c*32+t]
// s_j = j (j<4063), s_4063 = 4064.
// R4 skeleton (proven): block = 8 windows, 4 waves, 2 windows/wave, x LDS
// triple-buffer staged depth-2 via global_load_lds dwordx4, counted vmcnt +
// raw s_barrier. NEW: w register prefetch deepened to a 4-slot ring
// (depth-3), fully unrolled 21 channels (static slot indices) -> ~120 KB/CU
// in flight to cover queuing-inflated memory latency.

#define NF 4096
#define NC 21
#define WIN 32
#define OC 8
#define NWIN 4064
#define NKTOT (OC * NWIN)
#define DD (NC * WIN)       // 672
#define JB 8
#define NBLK (NWIN / JB)    // 508
#define XROWB 272           // 17 chunks * 16B per x row in LDS
#define XBUFB 9216          // 576 chunks * 16B per buffer

typedef short short8 __attribute__((ext_vector_type(8)));
typedef float f32x4 __attribute__((ext_vector_type(4)));

static __device__ __forceinline__ short f2bf(float f) {
  __bf16 h = (__bf16)f;
  return __builtin_bit_cast(short, h);
}
static __device__ __forceinline__ short8 pk8(float a, float b, float c, float d,
                                             float e, float f, float g, float h) {
  short8 v;
  v[0]=f2bf(a); v[1]=f2bf(b); v[2]=f2bf(c); v[3]=f2bf(d);
  v[4]=f2bf(e); v[5]=f2bf(f); v[6]=f2bf(g); v[7]=f2bf(h);
  return v;
}
static __device__ __forceinline__ short8 sel8(f32x4 a, f32x4 b, f32x4 c, int u) {
  switch (u & 3) {
    case 0:  return pk8(a[0],a[1],a[2],a[3],b[0],b[1],b[2],b[3]);
    case 1:  return pk8(a[1],a[2],a[3],b[0],b[1],b[2],b[3],c[0]);
    case 2:  return pk8(a[2],a[3],b[0],b[1],b[2],b[3],c[0],c[1]);
    default: return pk8(a[3],b[0],b[1],b[2],b[3],c[0],c[1],c[2]);
  }
}

#define VMW(N) asm volatile("s_waitcnt vmcnt(" #N ")" ::: "memory")
#define BAR() { __builtin_amdgcn_s_barrier(); __builtin_amdgcn_sched_barrier(0); }

#define GLL(GP, LOFF) \
  __builtin_amdgcn_global_load_lds( \
    (const __attribute__((address_space(1))) unsigned int*)(GP), \
    (__attribute__((address_space(3))) unsigned int*)(xlds + (LOFF)), 16, 0, 0)

__global__ __launch_bounds__(256) void fb_deep(const float* __restrict__ x,
                                               const float* __restrict__ w,
                                               float* __restrict__ out) {
  __shared__ __align__(16) char xlds[3 * XBUFB];
  const int lane = threadIdx.x & 63;
  const int wv   = threadIdx.x >> 6;

  // bijective XCD swizzle (nwg=508: q=63, r=4)
  const int orig = blockIdx.x;
  const int xcd = orig & 7, idx = orig >> 3;
  const int blk = (xcd < 4 ? xcd * 64 : 256 + (xcd - 4) * 63) + idx;
  const int j0 = blk * JB;
  const int a0 = (j0 < NF - 68) ? j0 : (NF - 68);   // staged span base

  const int n  = lane & 15;
  const int o  = n & 7;
  const int Ck = (lane >> 4) * 2;
  const int boff0 = n * XROWB, boff1 = (16 + n) * XROWB;

  const int jg0 = j0 + 2 * wv, jg1 = jg0 + 1;
  const int s1v = (jg1 == NWIN - 1) ? (NF - WIN) : jg1;
  const int rj0 = jg0 - a0, rj1 = s1v - a0;
  const int u0 = rj0 & 3, u1 = rj1 & 3;
  const int Cw0 = rj0 >> 2, Cw1 = rj1 >> 2;

  // x staging coords: chunks i = 2wv, 2wv+1 per wave; wave 0 also i=8
  const int i0 = 2 * wv, i1 = 2 * wv + 1;
  int q0 = i0 * 64 + lane, q1 = i1 * 64 + lane, q2 = 512 + lane;
  if (q2 > 543) q2 = 543;                // clamped dup-writes land in row pad
  const int b0 = q0 / 17, p0 = q0 - b0 * 17;
  const int b1 = q1 / 17, p1 = q1 - b1 * 17;
  const int b2 = q2 / 17, p2 = q2 - b2 * 17;
  const float* xs0 = x + (size_t)b0 * (NC * NF) + a0 + p0 * 4;
  const float* xs1 = x + (size_t)b1 * (NC * NF) + a0 + p1 * 4;
  const float* xs2 = x + (size_t)b2 * (NC * NF) + a0 + p2 * 4;
  const int l0 = i0 * 1024, l1 = i1 * 1024, l2 = 8 * 1024;

  const float* wb0 = w + ((size_t)jg0 * OC + o) * DD + Ck * 4;
  const float* wb1 = w + ((size_t)jg1 * OC + o) * DD + Ck * 4;

  f32x4 acc00 = {0,0,0,0}, acc01 = {0,0,0,0}, acc10 = {0,0,0,0}, acc11 = {0,0,0,0};

  // w ring: 4 slots (A,B,C,D), each = 4 f32x4 (2 windows x 2 halves)
  f32x4 wA0a, wA0b, wA1a, wA1b, wB0a, wB0b, wB1a, wB1b;
  f32x4 wC0a, wC0b, wC1a, wC1b, wD0a, wD0b, wD1a, wD1b;

#define STG(CH, NB) { \
    GLL(xs0 + (CH) * NF, (NB) * XBUFB + l0); \
    GLL(xs1 + (CH) * NF, (NB) * XBUFB + l1); \
    if (wv == 0) { GLL(xs2 + (CH) * NF, (NB) * XBUFB + l2); } }

#define LOADW(CH, P) { \
    w##P##0a = *(const f32x4*)(wb0 + (CH) * WIN); \
    w##P##0b = *(const f32x4*)(wb0 + (CH) * WIN + 4); \
    w##P##1a = *(const f32x4*)(wb1 + (CH) * WIN); \
    w##P##1b = *(const f32x4*)(wb1 + (CH) * WIN + 4); }

#define COMPUTE(C, P) { \
    const char* xb_ = xlds + ((C) % 3) * XBUFB; \
    { short8 fbw = pk8(w##P##0a[0],w##P##0a[1],w##P##0a[2],w##P##0a[3], \
                       w##P##0b[0],w##P##0b[1],w##P##0b[2],w##P##0b[3]); \
      int off = boff0 + (Cw0 + Ck) * 16; \
      f32x4 ra = *(const f32x4*)(xb_ + off); \
      f32x4 rb = *(const f32x4*)(xb_ + off + 16); \
      f32x4 rc = *(const f32x4*)(xb_ + off + 32); \
      acc00 = __builtin_amdgcn_mfma_f32_16x16x32_bf16(sel8(ra,rb,rc,u0), fbw, acc00, 0,0,0); \
      off = boff1 + (Cw0 + Ck) * 16; \
      ra = *(const f32x4*)(xb_ + off); \
      rb = *(const f32x4*)(xb_ + off + 16); \
      rc = *(const f32x4*)(xb_ + off + 32); \
      acc01 = __builtin_amdgcn_mfma_f32_16x16x32_bf16(sel8(ra,rb,rc,u0), fbw, acc01, 0,0,0); } \
    { short8 fbw = pk8(w##P##1a[0],w##P##1a[1],w##P##1a[2],w##P##1a[3], \
                       w##P##1b[0],w##P##1b[1],w##P##1b[2],w##P##1b[3]); \
      int off = boff0 + (Cw1 + Ck) * 16; \
      f32x4 ra = *(const f32x4*)(xb_ + off); \
      f32x4 rb = *(const f32x4*)(xb_ + off + 16); \
      f32x4 rc = *(const f32x4*)(xb_ + off + 32); \
      acc10 = __builtin_amdgcn_mfma_f32_16x16x32_bf16(sel8(ra,rb,rc,u1), fbw, acc10, 0,0,0); \
      off = boff1 + (Cw1 + Ck) * 16; \
      ra = *(const f32x4*)(xb_ + off); \
      rb = *(const f32x4*)(xb_ + off + 16); \
      rc = *(const f32x4*)(xb_ + off + 32); \
      acc11 = __builtin_amdgcn_mfma_f32_16x16x32_bf16(sel8(ra,rb,rc,u1), fbw, acc11, 0,0,0); } }

// BODY(c, CUR, DST): issue stage(c+2) + w(c+3), then compute channel c.
#define BODY(C, CUR, DST) { \
    if ((C) + 2 <= 20) { STG((C) + 2, ((C) + 2) % 3); } \
    if ((C) + 3 <= 20) { LOADW((C) + 3, DST); } \
    COMPUTE(C, CUR); }

#define WMID() { if (wv == 0) { VMW(11); } else { VMW(10); } }
#define W19()  { if (wv == 0) { VMW(7);  } else { VMW(6);  } }

  // ---- prologue: S0,S1 staged; W0,W1,W2 in flight (issue order matters) ----
  STG(0, 0); STG(1, 1);
  LOADW(0, A); LOADW(1, B); LOADW(2, C);

  VMW(8);  BAR(); BODY(0,  A, D);
  WMID();  BAR(); BODY(1,  B, A);
  WMID();  BAR(); BODY(2,  C, B);
  WMID();  BAR(); BODY(3,  D, C);
  WMID();  BAR(); BODY(4,  A, D);
  WMID();  BAR(); BODY(5,  B, A);
  WMID();  BAR(); BODY(6,  C, B);
  WMID();  BAR(); BODY(7,  D, C);
  WMID();  BAR(); BODY(8,  A, D);
  WMID();  BAR(); BODY(9,  B, A);
  WMID();  BAR(); BODY(10, C, B);
  WMID();  BAR(); BODY(11, D, C);
  WMID();  BAR(); BODY(12, A, D);
  WMID();  BAR(); BODY(13, B, A);
  WMID();  BAR(); BODY(14, C, B);
  WMID();  BAR(); BODY(15, D, C);
  WMID();  BAR(); BODY(16, A, D);
  WMID();  BAR(); BODY(17, B, A);     // last LOADW: channel 20 -> slot A
  WMID();  BAR(); BODY(18, C, B);     // last STG: channel 20 -> buf 2
  W19();   BAR(); BODY(19, D, C);
  VMW(0);  BAR(); BODY(20, A, D);

#undef BODY
#undef COMPUTE
#undef LOADW
#undef STG

  if (n < 8) {
    const int m0 = (lane >> 4) * 4;
    #pragma unroll
    for (int e = 0; e < 4; ++e) {
      out[(size_t)(m0 + e)      * NKTOT + (size_t)jg0 * OC + n] = acc00[e];
      out[(size_t)(m0 + e + 16) * NKTOT + (size_t)jg0 * OC + n] = acc01[e];
      out[(size_t)(m0 + e)      * NKTOT + (size_t)jg1 * OC + n] = acc10[e];
      out[(size_t)(m0 + e + 16) * NKTOT + (size_t)jg1 * OC + n] = acc11[e];
    }
  }
}

extern "C" void kernel_launch(void* const* d_in, const int* in_sizes, int n_in,
                              void* d_out, int out_size, void* d_ws, size_t ws_size,
                              hipStream_t stream) {
  const float* x = (const float*)d_in[0];
  const float* w = (const float*)d_in[1];
  float* out = (float*)d_out;
  dim3 grid(NBLK), block(256);
  hipLaunchKernelGGL(fb_deep, grid, block, 0, stream, x, w, out);
}